// Round 1
// baseline (84.392 us; speedup 1.0000x reference)
//
#include <hip/hip_runtime.h>
#include <cmath>

#define BB 16
#define CC_ 8
#define HH 512
#define WW 512
#define NBINS 15

// LDS one-hot map: 34 rows (tile rows -1..32), stride 35 dwords (cols -1..32 -> idx 0..33)
// stride 35 chosen so wave column-sum reads land ~conflict-free (3*ty+4*tx pattern).
#define OH_STRIDE 35

__device__ __forceinline__ float comp4(const float4 v, int i){
  return (i==0)?v.x:((i==1)?v.y:((i==2)?v.z:v.w));
}

// softmax over 8 logits -> probs p[], argmax (first-max semantics, matching jnp.argmax)
__device__ __forceinline__ void softmax8(const float* l, float* p, int& pc){
  float m = l[0];
#pragma unroll
  for(int c=1;c<CC_;c++) m = fmaxf(m, l[c]);
  float e[CC_]; float S = 0.f;
#pragma unroll
  for(int c=0;c<CC_;c++){ e[c] = expf(l[c]-m); S += e[c]; }
#pragma unroll
  for(int c=0;c<CC_;c++) p[c] = e[c]/S;   // per-channel IEEE div: match reference rounding
  pc = 0; float best = p[0];
#pragma unroll
  for(int c=1;c<CC_;c++){ if(p[c] > best){ best = p[c]; pc = c; } }
}

__global__ void nectar_binning_kernel(const float* __restrict__ logits,
                                      const float* __restrict__ vf,
                                      float* __restrict__ out){
  __shared__ float s_vf[CC_*9*16];                 // bins padded 15 -> 16
  __shared__ unsigned int s_oneh[34*OH_STRIDE];    // nibble one-hot of argmax (0 for OOB)

  const int tid = threadIdx.x;
  const int bx = blockIdx.x, by = blockIdx.y, bz = blockIdx.z;
  const int h0 = by*32, w0 = bx*32;

  // stage calibration table into LDS
  for (int i = tid; i < CC_*9*NBINS; i += 256){
    int q = i / NBINS, r = i - q*NBINS;
    s_vf[q*16 + r] = vf[i];
  }

  const int tx = tid & 7;    // w-quad index (4 pixels along w)
  const int ty = tid >> 3;   // row 0..31
  const int gh = h0 + ty;
  const int gw = w0 + tx*4;

  // ---- interior: load 8 channels x 4 pixels (coalesced float4) ----
  float4 lv[CC_];
#pragma unroll
  for(int c=0;c<CC_;c++)
    lv[c] = *reinterpret_cast<const float4*>(logits + (((bz*CC_ + c)*HH + gh)*WW + gw));

  int bins[4][CC_];
  int pcv[4];
#pragma unroll
  for(int i=0;i<4;i++){
    float l[CC_], p[CC_]; int pc;
#pragma unroll
    for(int c=0;c<CC_;c++) l[c] = comp4(lv[c], i);
    softmax8(l, p, pc);
    pcv[i] = pc;
#pragma unroll
    for(int c=0;c<CC_;c++){
      int b = (int)(p[c]*15.0f);              // trunc == floor for p>=0
      bins[i][c] = b > 14 ? 14 : b;           // clip top (p==1 -> 15 -> 14)
    }
    s_oneh[(ty+1)*OH_STRIDE + (4*tx+i+1)] = 1u << (4*pc);
  }

  // ---- halo ring: 132 pixels, argmax only; OOB -> 0 (contributes to neither count) ----
  if (tid < 132){
    int r, cc;
    if (tid < 34){ r = -1; cc = tid - 1; }
    else if (tid < 68){ r = 32; cc = tid - 35; }
    else if (tid < 100){ r = tid - 68; cc = -1; }
    else { r = tid - 100; cc = 32; }
    const int hh = h0 + r, ww = w0 + cc;
    unsigned int oh = 0;
    if (hh >= 0 && hh < HH && ww >= 0 && ww < WW){
      float l[CC_], p[CC_]; int pc;
#pragma unroll
      for(int c=0;c<CC_;c++) l[c] = logits[((bz*CC_ + c)*HH + hh)*WW + ww];
      softmax8(l, p, pc);
      oh = 1u << (4*pc);
    }
    s_oneh[(r+1)*OH_STRIDE + (cc+1)] = oh;
  }

  __syncthreads();

  // ---- 3x3 neighbor histogram via nibble one-hot column sums ----
  unsigned int cs[6];
#pragma unroll
  for(int k=0;k<6;k++){
    int cidx = 4*tx + k;
    cs[k] = s_oneh[ ty   *OH_STRIDE + cidx]
          + s_oneh[(ty+1)*OH_STRIDE + cidx]
          + s_oneh[(ty+2)*OH_STRIDE + cidx];
  }

  float4 o[CC_];
#pragma unroll
  for(int i=0;i<4;i++){
    // 3x3 window sum minus center one-hot -> per-class neighbor counts in nibbles
    unsigned int acc = cs[i] + cs[i+1] + cs[i+2] - (1u << (4*pcv[i]));
    unsigned int valid = (acc * 0x11111111u) >> 28;   // # valid neighbors (<=8, no nibble overflow)
    float v[CC_]; float S2 = 0.f;
#pragma unroll
    for(int c=0;c<CC_;c++){
      unsigned int mc = (acc >> (4*c)) & 0xFu;                 // neighbors predicted c
      unsigned int nn = (c == pcv[i]) ? mc : (valid - mc);     // matching-value count
      float t = s_vf[c*144 + (nn<<4) + bins[i][c]];
      v[c] = t; S2 += t;
    }
    float r2 = 1.0f / S2;    // normalization not boundary-sensitive: rcp-mul ok (<=1ulp)
#pragma unroll
    for(int c=0;c<CC_;c++){
      float res = v[c]*r2;
      if(i==0) o[c].x = res; else if(i==1) o[c].y = res; else if(i==2) o[c].z = res; else o[c].w = res;
    }
  }
#pragma unroll
  for(int c=0;c<CC_;c++)
    *reinterpret_cast<float4*>(out + (((bz*CC_ + c)*HH + gh)*WW + gw)) = o[c];
}

extern "C" void kernel_launch(void* const* d_in, const int* in_sizes, int n_in,
                              void* d_out, int out_size, void* d_ws, size_t ws_size,
                              hipStream_t stream){
  const float* logits = (const float*)d_in[0];
  const float* vf     = (const float*)d_in[1];
  float* out          = (float*)d_out;
  dim3 grid(WW/32, HH/32, BB);
  nectar_binning_kernel<<<grid, 256, 0, stream>>>(logits, vf, out);
}

// Round 2
// 65.332 us; speedup vs baseline: 1.2917x; 1.2917x over previous
//
#include <hip/hip_runtime.h>
#include <cmath>

#define CC_ 8
#define HH 512
#define WW 512
#define TW 64         // tile width
#define TH 32         // tile height
#define OHS 67        // onehot LDS stride in dwords (odd -> conflict-light)
#define NWG ((WW/TW)*(HH/TH)*16)   // 8*16*16 = 2048

__device__ __forceinline__ float comp4(const float4 v, int i){
  return (i==0)?v.x:((i==1)?v.y:((i==2)?v.z:v.w));
}

__global__ __launch_bounds__(256, 4) void nectar_binning_kernel(
    const float* __restrict__ logits,
    const float* __restrict__ vf,
    float* __restrict__ out){
  __shared__ float s_vf[CC_*9*16];                 // bins padded 15 -> 16
  __shared__ unsigned int s_oneh[(TH+2)*OHS];      // nibble one-hot of argmax (0 for OOB)

  const int tid = threadIdx.x;

  // XCD-bijective swizzle: NWG%8==0, chunk = NWG/8 consecutive virt ids per XCD
  const int lin  = blockIdx.x;
  const int virt = (lin & 7) * (NWG/8) + (lin >> 3);
  const int bz   = virt >> 7;            // 128 tiles per batch
  const int rem  = virt & 127;
  const int h0   = (rem >> 3) * TH;      // 16 tile-rows
  const int w0   = (rem & 7) * TW;       // 8 tile-cols

  // stage calibration table
  for (int i = tid; i < CC_*9*15; i += 256){
    int q = i / 15, r = i - q*15;
    s_vf[q*16 + r] = vf[i];
  }

  const int tx = tid & 15;               // w-quad (4 px)
  const int ty = tid >> 4;               // 16 row-threads; strips k=0,1 -> rows ty, ty+16
  const long base_b = (long)bz * (CC_*HH*WW);

  unsigned int binw[8];                  // 2 strips x 4 px, 8 bins packed in nibbles

  #pragma unroll
  for (int k = 0; k < 2; ++k){
    const int r  = ty + 16*k;
    const int gh = h0 + r;
    const int gw = w0 + 4*tx;
    const float* lp = logits + base_b + (long)gh*WW + gw;
    float4 lv[CC_];
    #pragma unroll
    for (int c = 0; c < CC_; ++c)
      lv[c] = *reinterpret_cast<const float4*>(lp + (long)c*(HH*WW));

    #pragma unroll
    for (int i = 0; i < 4; ++i){
      float l[CC_];
      #pragma unroll
      for (int c = 0; c < CC_; ++c) l[c] = comp4(lv[c], i);
      float m = l[0];
      #pragma unroll
      for (int c = 1; c < CC_; ++c) m = fmaxf(m, l[c]);
      float e[CC_]; float S = 0.f;
      #pragma unroll
      for (int c = 0; c < CC_; ++c){ e[c] = expf(l[c]-m); S += e[c]; }

      // argmax over e (first-max) + second-max for tie guard (e_max == 1.0f)
      float b1 = e[0], b2 = 0.f; int pc = 0;
      #pragma unroll
      for (int c = 1; c < CC_; ++c){
        bool gt = e[c] > b1;
        b2 = gt ? b1 : fmaxf(b2, e[c]);
        pc = gt ? c : pc;
        b1 = gt ? e[c] : b1;
      }

      // fast bins: t = e * (15 * rcp(S)), error <~1e-5 rel; guard 1e-4 to nonzero ints
      float r15 = 15.0f * __builtin_amdgcn_rcpf(S);
      unsigned int bw = 0;
      bool bad = (b1 - b2) < 1e-6f * b1;
      #pragma unroll
      for (int c = 0; c < CC_; ++c){
        float t = e[c] * r15;
        float rn = rintf(t);
        bad = bad || (rn > 0.5f && fabsf(t - rn) < 1e-4f);
        int b = (int)t; b = b > 14 ? 14 : b;
        bw |= (unsigned)b << (4*c);
      }
      if (bad){
        // exact reference path (bitwise match): IEEE divs, floor(p*15), argmax over p
        bw = 0;
        float p[CC_];
        #pragma unroll
        for (int c = 0; c < CC_; ++c) p[c] = e[c]/S;
        float best = p[0]; pc = 0;
        #pragma unroll
        for (int c = 1; c < CC_; ++c){ if (p[c] > best){ best = p[c]; pc = c; } }
        #pragma unroll
        for (int c = 0; c < CC_; ++c){
          int b = (int)(p[c]*15.0f); b = b > 14 ? 14 : b;
          bw |= (unsigned)b << (4*c);
        }
      }
      binw[4*k+i] = bw;
      s_oneh[(r+1)*OHS + 4*tx + i + 1] = 1u << (4*pc);
    }
  }

  // ---- halo ring: 196 px, argmax only (no softmax needed except rare tie) ----
  {
    int hi = tid;
    if (hi < 196){
      int r, c;
      if      (hi < 66){ r = -1;      c = hi - 1;  }
      else if (hi < 132){ r = TH;     c = hi - 67; }
      else if (hi < 164){ r = hi-132; c = -1;      }
      else              { r = hi-164; c = TW;      }
      const int hh = h0 + r, ww = w0 + c;
      unsigned int oh = 0u;
      if (hh >= 0 && hh < HH && ww >= 0 && ww < WW){
        float l[CC_];
        const float* lp = logits + base_b + (long)hh*WW + ww;
        #pragma unroll
        for (int c2 = 0; c2 < CC_; ++c2) l[c2] = lp[(long)c2*(HH*WW)];
        float b1 = l[0], b2 = -1e30f; int pc = 0;
        #pragma unroll
        for (int c2 = 1; c2 < CC_; ++c2){
          bool gt = l[c2] > b1;
          b2 = gt ? b1 : fmaxf(b2, l[c2]);
          pc = gt ? c2 : pc;
          b1 = gt ? l[c2] : b1;
        }
        if (b1 - b2 < 1e-5f){   // rounding-collision risk: exact reference path
          float e[CC_]; float S = 0.f;
          #pragma unroll
          for (int c2 = 0; c2 < CC_; ++c2){ e[c2] = expf(l[c2]-b1); S += e[c2]; }
          float p[CC_];
          #pragma unroll
          for (int c2 = 0; c2 < CC_; ++c2) p[c2] = e[c2]/S;
          float best = p[0]; pc = 0;
          #pragma unroll
          for (int c2 = 1; c2 < CC_; ++c2){ if (p[c2] > best){ best = p[c2]; pc = c2; } }
        }
        oh = 1u << (4*pc);
      }
      s_oneh[(r+1)*OHS + c + 1] = oh;
    }
  }

  __syncthreads();

  // ---- epilogue: 3x3 nibble histogram, gather, normalize, store ----
  #pragma unroll
  for (int k = 0; k < 2; ++k){
    const int r  = ty + 16*k;
    const int gh = h0 + r;
    const int gw = w0 + 4*tx;
    unsigned int cs[6];
    #pragma unroll
    for (int kk = 0; kk < 6; ++kk){
      int cidx = 4*tx + kk;
      cs[kk] = s_oneh[ r   *OHS + cidx]
             + s_oneh[(r+1)*OHS + cidx]
             + s_oneh[(r+2)*OHS + cidx];
    }
    float4 o[CC_];
    #pragma unroll
    for (int i = 0; i < 4; ++i){
      unsigned int ctr = s_oneh[(r+1)*OHS + 4*tx + i + 1];     // own one-hot
      unsigned int acc = cs[i] + cs[i+1] + cs[i+2] - ctr;      // 8 neighbors, per-class nibbles
      unsigned int valid = (acc * 0x11111111u) >> 28;          // # valid neighbors
      unsigned int bw = binw[4*k+i];
      float v[CC_]; float S2 = 0.f;
      #pragma unroll
      for (int c = 0; c < CC_; ++c){
        unsigned int nc = (acc >> (4*c)) & 0xFu;
        unsigned int nn = ((ctr >> (4*c)) & 1u) ? nc : (valid - nc);
        unsigned int b  = (bw  >> (4*c)) & 0xFu;
        float t = s_vf[c*144 + (nn<<4) + b];
        v[c] = t; S2 += t;
      }
      float r2 = 1.0f / S2;
      #pragma unroll
      for (int c = 0; c < CC_; ++c){
        float res = v[c]*r2;
        if(i==0) o[c].x = res; else if(i==1) o[c].y = res; else if(i==2) o[c].z = res; else o[c].w = res;
      }
    }
    #pragma unroll
    for (int c = 0; c < CC_; ++c)
      *reinterpret_cast<float4*>(out + base_b + (long)c*(HH*WW) + (long)gh*WW + gw) = o[c];
  }
}

extern "C" void kernel_launch(void* const* d_in, const int* in_sizes, int n_in,
                              void* d_out, int out_size, void* d_ws, size_t ws_size,
                              hipStream_t stream){
  const float* logits = (const float*)d_in[0];
  const float* vf     = (const float*)d_in[1];
  float* out          = (float*)d_out;
  nectar_binning_kernel<<<dim3(NWG), 256, 0, stream>>>(logits, vf, out);
}

// Round 3
// 62.337 us; speedup vs baseline: 1.3538x; 1.0481x over previous
//
#include <hip/hip_runtime.h>
#include <cmath>

#define CC_ 8
#define HH 512
#define WW 512
#define TW 64         // tile width
#define TH 32         // tile height
#define OHS 67        // onehot LDS stride in dwords
#define NWG ((WW/TW)*(HH/TH)*16)   // 8*16*16 = 2048
#define LOG2E 1.44269504088896340736f

__device__ __forceinline__ float comp4(const float4 v, int i){
  return (i==0)?v.x:((i==1)?v.y:((i==2)?v.z:v.w));
}

__global__ __launch_bounds__(256, 4) void nectar_binning_kernel(
    const float* __restrict__ logits,
    const float* __restrict__ vf,
    float* __restrict__ out){
  __shared__ float s_vf[CC_*144];                  // [c][bin][nn], addr = c*144 + b*9 + nn
  __shared__ unsigned int s_oneh[(TH+2)*OHS];      // nibble one-hot of argmax (0 for OOB)

  const int tid = threadIdx.x;

  // XCD-bijective swizzle: NWG%8==0
  const int lin  = blockIdx.x;
  const int virt = (lin & 7) * (NWG/8) + (lin >> 3);
  const int bz   = virt >> 7;            // 128 tiles per batch
  const int rem  = virt & 127;
  const int h0   = (rem >> 3) * TH;      // 16 tile-rows
  const int w0   = (rem & 7) * TW;       // 8 tile-cols

  const long base_b = (long)bz * (CC_*HH*WW);

  // stage calibration table, remapped: vf[(c*9+nn)*15+b] -> s_vf[c*144 + b*9 + nn]
  for (int i = tid; i < CC_*9*15; i += 256){
    int b = i % 15, q = i / 15;
    int nn = q % 9, c = q / 9;
    s_vf[c*144 + b*9 + nn] = vf[i];
  }

  // ---- halo: issue loads EARLY so latency hides under interior compute ----
  float hl[CC_]; bool hval = false; int hr = 0, hc = 0;
  if (tid < 196){
    int r, c;
    if      (tid < 66){ r = -1;       c = tid - 1;  }
    else if (tid < 132){ r = TH;      c = tid - 67; }
    else if (tid < 164){ r = tid-132; c = -1;       }
    else               { r = tid-164; c = TW;       }
    hr = r; hc = c;
    const int hh = h0 + r, ww = w0 + c;
    hval = (hh >= 0 && hh < HH && ww >= 0 && ww < WW);
    const int hhc = min(max(hh,0),HH-1), wwc = min(max(ww,0),WW-1);
    const float* lp = logits + base_b + (long)hhc*WW + wwc;
    #pragma unroll
    for (int c2 = 0; c2 < CC_; ++c2) hl[c2] = lp[(long)c2*(HH*WW)];
  }

  const int tx = tid & 15;               // w-quad (4 px)
  const int ty = tid >> 4;               // 16 row-threads; strips k=0,1 -> rows ty, ty+16

  unsigned int binw[8];                  // 2 strips x 4 px, 8 bins packed in nibbles

  #pragma unroll
  for (int k = 0; k < 2; ++k){
    const int r  = ty + 16*k;
    const int gh = h0 + r;
    const int gw = w0 + 4*tx;
    const float* lp = logits + base_b + (long)gh*WW + gw;
    float4 lv[CC_];
    #pragma unroll
    for (int c = 0; c < CC_; ++c)
      lv[c] = *reinterpret_cast<const float4*>(lp + (long)c*(HH*WW));

    #pragma unroll
    for (int i = 0; i < 4; ++i){
      float l[CC_], e[CC_];
      float S = 0.f;
      #pragma unroll
      for (int c = 0; c < CC_; ++c){
        l[c] = comp4(lv[c], i);
        e[c] = __builtin_amdgcn_exp2f(l[c] * LOG2E);   // no max-subtract: |l| small
        S += e[c];
      }
      // argmax over e (first-max) + runner-up for tie guard
      float b1 = e[0], b2 = 0.f; int pc = 0;
      #pragma unroll
      for (int c = 1; c < CC_; ++c){
        bool gt = e[c] > b1;
        b2 = gt ? b1 : fmaxf(b2, e[c]);
        pc = gt ? c : pc;
        b1 = gt ? e[c] : b1;
      }
      float r15 = 15.0f * __builtin_amdgcn_rcpf(S);
      unsigned int bw = 0;
      bool bad = (b1 - b2) < 1e-5f * b1;
      #pragma unroll
      for (int c = 0; c < CC_; ++c){
        float t = e[c] * r15;
        float rn = rintf(t);
        bad = bad || (rn > 0.5f && fabsf(t - rn) < 1e-4f);
        int b = (int)t; b = b > 14 ? 14 : b;
        bw |= (unsigned)b << (4*c);
      }
      if (bad){
        // exact reference path (bitwise anchor): max-subtract expf, IEEE divs
        float m = l[0];
        #pragma unroll
        for (int c = 1; c < CC_; ++c) m = fmaxf(m, l[c]);
        float ee[CC_]; float SS = 0.f;
        #pragma unroll
        for (int c = 0; c < CC_; ++c){ ee[c] = expf(l[c]-m); SS += ee[c]; }
        float p[CC_];
        #pragma unroll
        for (int c = 0; c < CC_; ++c) p[c] = ee[c]/SS;
        float best = p[0]; pc = 0;
        #pragma unroll
        for (int c = 1; c < CC_; ++c){ if (p[c] > best){ best = p[c]; pc = c; } }
        bw = 0;
        #pragma unroll
        for (int c = 0; c < CC_; ++c){
          int b = (int)(p[c]*15.0f); b = b > 14 ? 14 : b;
          bw |= (unsigned)b << (4*c);
        }
      }
      binw[4*k+i] = bw;
      s_oneh[(r+1)*OHS + 4*tx + i + 1] = 1u << (4*pc);
    }
  }

  // ---- halo argmax (loads already in flight since kernel top) ----
  if (tid < 196){
    unsigned int oh = 0u;
    if (hval){
      float b1 = hl[0], b2 = -1e30f; int pc = 0;
      #pragma unroll
      for (int c2 = 1; c2 < CC_; ++c2){
        bool gt = hl[c2] > b1;
        b2 = gt ? b1 : fmaxf(b2, hl[c2]);
        pc = gt ? c2 : pc;
        b1 = gt ? hl[c2] : b1;
      }
      if (b1 - b2 < 1e-5f){   // rounding-collision risk: exact reference path
        float e[CC_]; float S = 0.f;
        #pragma unroll
        for (int c2 = 0; c2 < CC_; ++c2){ e[c2] = expf(hl[c2]-b1); S += e[c2]; }
        float p[CC_];
        #pragma unroll
        for (int c2 = 0; c2 < CC_; ++c2) p[c2] = e[c2]/S;
        float best = p[0]; pc = 0;
        #pragma unroll
        for (int c2 = 1; c2 < CC_; ++c2){ if (p[c2] > best){ best = p[c2]; pc = c2; } }
      }
      oh = 1u << (4*pc);
    }
    s_oneh[(hr+1)*OHS + hc + 1] = oh;
  }

  __syncthreads();

  // ---- epilogue: 3x3 nibble histogram, gather, normalize, store ----
  #pragma unroll
  for (int k = 0; k < 2; ++k){
    const int r  = ty + 16*k;
    const int gh = h0 + r;
    const int gw = w0 + 4*tx;
    unsigned int cs[6];
    #pragma unroll
    for (int kk = 0; kk < 6; ++kk){
      int cidx = 4*tx + kk;
      cs[kk] = s_oneh[ r   *OHS + cidx]
             + s_oneh[(r+1)*OHS + cidx]
             + s_oneh[(r+2)*OHS + cidx];
    }
    float4 o[CC_];
    #pragma unroll
    for (int i = 0; i < 4; ++i){
      unsigned int ctr = s_oneh[(r+1)*OHS + 4*tx + i + 1];     // own one-hot
      unsigned int acc = cs[i] + cs[i+1] + cs[i+2] - ctr;      // 8 neighbors, per-class nibbles
      unsigned int valid = (acc * 0x11111111u) >> 28;          // # valid neighbors
      unsigned int bw = binw[4*k+i];
      float v[CC_]; float S2 = 0.f;
      #pragma unroll
      for (int c = 0; c < CC_; ++c){
        unsigned int nc = (acc >> (4*c)) & 0xFu;
        unsigned int nn = ((ctr >> (4*c)) & 1u) ? nc : (valid - nc);
        unsigned int b  = (bw  >> (4*c)) & 0xFu;
        float t = s_vf[c*144 + b*9 + nn];
        v[c] = t; S2 += t;
      }
      float r2 = 1.0f / S2;
      #pragma unroll
      for (int c = 0; c < CC_; ++c){
        float res = v[c]*r2;
        if(i==0) o[c].x = res; else if(i==1) o[c].y = res; else if(i==2) o[c].z = res; else o[c].w = res;
      }
    }
    #pragma unroll
    for (int c = 0; c < CC_; ++c)
      *reinterpret_cast<float4*>(out + base_b + (long)c*(HH*WW) + (long)gh*WW + gw) = o[c];
  }
}

extern "C" void kernel_launch(void* const* d_in, const int* in_sizes, int n_in,
                              void* d_out, int out_size, void* d_ws, size_t ws_size,
                              hipStream_t stream){
  const float* logits = (const float*)d_in[0];
  const float* vf     = (const float*)d_in[1];
  float* out          = (float*)d_out;
  nectar_binning_kernel<<<dim3(NWG), 256, 0, stream>>>(logits, vf, out);
}

// Round 5
// 53.264 us; speedup vs baseline: 1.5844x; 1.1703x over previous
//
#include <hip/hip_runtime.h>
#include <cmath>

#define CC_ 8
#define HH 512
#define WW 512
#define TW 64         // tile width
#define TH 32         // tile height
#define OHS 67        // onehot LDS stride in dwords
#define NWG ((WW/TW)*(HH/TH)*16)   // 8*16*16 = 2048
#define LOG2E 1.44269504088896340736f

typedef float vfloat4 __attribute__((ext_vector_type(4)));   // native vec for NT store

__device__ __forceinline__ float comp4(const float4 v, int i){
  return (i==0)?v.x:((i==1)?v.y:((i==2)?v.z:v.w));
}

// fast bins + argmax with guarded bitwise-exact fallback (identical math to R3 pass)
__device__ __forceinline__ void px_bins(const float* l, unsigned int& bw_out, int& pc_out){
  float e[CC_]; float S = 0.f;
  #pragma unroll
  for (int c = 0; c < CC_; ++c){
    e[c] = __builtin_amdgcn_exp2f(l[c] * LOG2E);   // no max-subtract: |l| small
    S += e[c];
  }
  float b1 = e[0], b2 = 0.f; int pc = 0;
  #pragma unroll
  for (int c = 1; c < CC_; ++c){
    bool gt = e[c] > b1;
    b2 = gt ? b1 : fmaxf(b2, e[c]);
    pc = gt ? c : pc;
    b1 = gt ? e[c] : b1;
  }
  float r15 = 15.0f * __builtin_amdgcn_rcpf(S);
  unsigned int bw = 0;
  bool bad = (b1 - b2) < 1e-5f * b1;
  #pragma unroll
  for (int c = 0; c < CC_; ++c){
    float t = e[c] * r15;
    float rn = rintf(t);
    bad = bad || (rn > 0.5f && fabsf(t - rn) < 1e-4f);
    int b = (int)t; b = b > 14 ? 14 : b;
    bw |= (unsigned)b << (4*c);
  }
  if (bad){
    // exact reference path (bitwise anchor): max-subtract expf, IEEE divs
    float m = l[0];
    #pragma unroll
    for (int c = 1; c < CC_; ++c) m = fmaxf(m, l[c]);
    float ee[CC_]; float SS = 0.f;
    #pragma unroll
    for (int c = 0; c < CC_; ++c){ ee[c] = expf(l[c]-m); SS += ee[c]; }
    float p[CC_];
    #pragma unroll
    for (int c = 0; c < CC_; ++c) p[c] = ee[c]/SS;
    float best = p[0]; pc = 0;
    #pragma unroll
    for (int c = 1; c < CC_; ++c){ if (p[c] > best){ best = p[c]; pc = c; } }
    bw = 0;
    #pragma unroll
    for (int c = 0; c < CC_; ++c){
      int b = (int)(p[c]*15.0f); b = b > 14 ? 14 : b;
      bw |= (unsigned)b << (4*c);
    }
  }
  bw_out = bw; pc_out = pc;
}

__global__ __launch_bounds__(256, 4) void nectar_binning_kernel(
    const float* __restrict__ logits,
    const float* __restrict__ vf,
    float* __restrict__ out){
  __shared__ float s_vf[CC_*144];                  // [c][bin][nn]: c*144 + b*9 + nn
  __shared__ unsigned int s_oneh[(TH+2)*OHS];

  const int tid = threadIdx.x;

  // XCD-bijective swizzle
  const int lin  = blockIdx.x;
  const int virt = (lin & 7) * (NWG/8) + (lin >> 3);
  const int bz   = virt >> 7;
  const int rem  = virt & 127;
  const int h0   = (rem >> 3) * TH;
  const int w0   = (rem & 7) * TW;
  const long base_b = (long)bz * (CC_*HH*WW);

  const int tx = tid & 15;
  const int ty = tid >> 4;

  // ---- issue ALL global loads up front: strip0 + strip1 (8 float4 each), then halo ----
  const int gw = w0 + 4*tx;
  const float* lp0 = logits + base_b + (long)(h0 + ty     )*WW + gw;
  const float* lp1 = logits + base_b + (long)(h0 + ty + 16)*WW + gw;
  float4 lv0[CC_], lv1[CC_];
  #pragma unroll
  for (int c = 0; c < CC_; ++c) lv0[c] = *reinterpret_cast<const float4*>(lp0 + (long)c*(HH*WW));
  #pragma unroll
  for (int c = 0; c < CC_; ++c) lv1[c] = *reinterpret_cast<const float4*>(lp1 + (long)c*(HH*WW));

  float hl[CC_]; bool hval = false; int hr = 0, hc = 0;
  if (tid < 196){
    int r, c;
    if      (tid < 66){ r = -1;       c = tid - 1;  }
    else if (tid < 132){ r = TH;      c = tid - 67; }
    else if (tid < 164){ r = tid-132; c = -1;       }
    else               { r = tid-164; c = TW;       }
    hr = r; hc = c;
    const int hh = h0 + r, ww = w0 + c;
    hval = (hh >= 0 && hh < HH && ww >= 0 && ww < WW);
    const int hhc = min(max(hh,0),HH-1), wwc = min(max(ww,0),WW-1);
    const float* lp = logits + base_b + (long)hhc*WW + wwc;
    #pragma unroll
    for (int c2 = 0; c2 < CC_; ++c2) hl[c2] = lp[(long)c2*(HH*WW)];
  }

  // stage calibration table (LDS writes overlap load latency)
  for (int i = tid; i < CC_*9*15; i += 256){
    int b = i % 15, q = i / 15;
    int nn = q % 9, c = q / 9;
    s_vf[c*144 + b*9 + nn] = vf[i];
  }

  unsigned int binw[8];

  // ---- strip 0 ----
  #pragma unroll
  for (int i = 0; i < 4; ++i){
    float l[CC_];
    #pragma unroll
    for (int c = 0; c < CC_; ++c) l[c] = comp4(lv0[c], i);
    int pc; px_bins(l, binw[i], pc);
    s_oneh[(ty+1)*OHS + 4*tx + i + 1] = 1u << (4*pc);
  }
  // ---- strip 1 ----
  #pragma unroll
  for (int i = 0; i < 4; ++i){
    float l[CC_];
    #pragma unroll
    for (int c = 0; c < CC_; ++c) l[c] = comp4(lv1[c], i);
    int pc; px_bins(l, binw[4+i], pc);
    s_oneh[(ty+17)*OHS + 4*tx + i + 1] = 1u << (4*pc);
  }

  // ---- halo argmax ----
  if (tid < 196){
    unsigned int oh = 0u;
    if (hval){
      float b1 = hl[0], b2 = -1e30f; int pc = 0;
      #pragma unroll
      for (int c2 = 1; c2 < CC_; ++c2){
        bool gt = hl[c2] > b1;
        b2 = gt ? b1 : fmaxf(b2, hl[c2]);
        pc = gt ? c2 : pc;
        b1 = gt ? hl[c2] : b1;
      }
      if (b1 - b2 < 1e-5f){
        float e[CC_]; float S = 0.f;
        #pragma unroll
        for (int c2 = 0; c2 < CC_; ++c2){ e[c2] = expf(hl[c2]-b1); S += e[c2]; }
        float p[CC_];
        #pragma unroll
        for (int c2 = 0; c2 < CC_; ++c2) p[c2] = e[c2]/S;
        float best = p[0]; pc = 0;
        #pragma unroll
        for (int c2 = 1; c2 < CC_; ++c2){ if (p[c2] > best){ best = p[c2]; pc = c2; } }
      }
      oh = 1u << (4*pc);
    }
    s_oneh[(hr+1)*OHS + hc + 1] = oh;
  }

  __syncthreads();

  // ---- epilogue: 3x3 nibble histogram, gather, normalize, NT store ----
  #pragma unroll
  for (int k = 0; k < 2; ++k){
    const int r  = ty + 16*k;
    const int gh = h0 + r;
    unsigned int cs[6];
    #pragma unroll
    for (int kk = 0; kk < 6; ++kk){
      int cidx = 4*tx + kk;
      cs[kk] = s_oneh[ r   *OHS + cidx]
             + s_oneh[(r+1)*OHS + cidx]
             + s_oneh[(r+2)*OHS + cidx];
    }
    float4 o[CC_];
    #pragma unroll
    for (int i = 0; i < 4; ++i){
      unsigned int ctr = s_oneh[(r+1)*OHS + 4*tx + i + 1];
      unsigned int acc = cs[i] + cs[i+1] + cs[i+2] - ctr;
      unsigned int valid = (acc * 0x11111111u) >> 28;
      unsigned int bw = binw[4*k+i];
      float v[CC_]; float S2 = 0.f;
      #pragma unroll
      for (int c = 0; c < CC_; ++c){
        unsigned int nc = (acc >> (4*c)) & 0xFu;
        unsigned int nn = ((ctr >> (4*c)) & 1u) ? nc : (valid - nc);
        unsigned int b  = (bw  >> (4*c)) & 0xFu;
        float t = s_vf[c*144 + b*9 + nn];
        v[c] = t; S2 += t;
      }
      float r2 = 1.0f / S2;
      #pragma unroll
      for (int c = 0; c < CC_; ++c){
        float res = v[c]*r2;
        if(i==0) o[c].x = res; else if(i==1) o[c].y = res; else if(i==2) o[c].z = res; else o[c].w = res;
      }
    }
    #pragma unroll
    for (int c = 0; c < CC_; ++c){
      vfloat4 nv = { o[c].x, o[c].y, o[c].z, o[c].w };
      __builtin_nontemporal_store(nv,
        reinterpret_cast<vfloat4*>(out + base_b + (long)c*(HH*WW) + (long)gh*WW + gw));
    }
  }
}

extern "C" void kernel_launch(void* const* d_in, const int* in_sizes, int n_in,
                              void* d_out, int out_size, void* d_ws, size_t ws_size,
                              hipStream_t stream){
  const float* logits = (const float*)d_in[0];
  const float* vf     = (const float*)d_in[1];
  float* out          = (float*)d_out;
  nectar_binning_kernel<<<dim3(NWG), 256, 0, stream>>>(logits, vf, out);
}

// Round 6
// 51.755 us; speedup vs baseline: 1.6306x; 1.0292x over previous
//
#include <hip/hip_runtime.h>
#include <cmath>

#define CC_ 8
#define HH 512
#define WW 512
#define TW 32         // tile width
#define TH 32         // tile height
#define OHS 35        // onehot LDS stride in dwords
#define NWG ((WW/TW)*(HH/TH)*16)   // 16*16*16 = 4096
#define LOG2E 1.44269504088896340736f

typedef float vfloat4 __attribute__((ext_vector_type(4)));   // native vec for NT store

__device__ __forceinline__ float comp4(const float4 v, int i){
  return (i==0)?v.x:((i==1)?v.y:((i==2)?v.z:v.w));
}

// fast bins + argmax with guarded bitwise-exact fallback (identical math to R5 pass)
__device__ __forceinline__ void px_bins(const float* l, unsigned int& bw_out, int& pc_out){
  float e[CC_]; float S = 0.f;
  #pragma unroll
  for (int c = 0; c < CC_; ++c){
    e[c] = __builtin_amdgcn_exp2f(l[c] * LOG2E);   // no max-subtract: |l| small
    S += e[c];
  }
  float b1 = e[0], b2 = 0.f; int pc = 0;
  #pragma unroll
  for (int c = 1; c < CC_; ++c){
    bool gt = e[c] > b1;
    b2 = gt ? b1 : fmaxf(b2, e[c]);
    pc = gt ? c : pc;
    b1 = gt ? e[c] : b1;
  }
  float r15 = 15.0f * __builtin_amdgcn_rcpf(S);
  unsigned int bw = 0;
  bool bad = (b1 - b2) < 1e-5f * b1;
  #pragma unroll
  for (int c = 0; c < CC_; ++c){
    float t = e[c] * r15;
    float rn = rintf(t);
    bad = bad || (rn > 0.5f && fabsf(t - rn) < 1e-4f);
    int b = (int)t; b = b > 14 ? 14 : b;
    bw |= (unsigned)b << (4*c);
  }
  if (bad){
    // exact reference path (bitwise anchor): max-subtract expf, IEEE divs
    float m = l[0];
    #pragma unroll
    for (int c = 1; c < CC_; ++c) m = fmaxf(m, l[c]);
    float ee[CC_]; float SS = 0.f;
    #pragma unroll
    for (int c = 0; c < CC_; ++c){ ee[c] = expf(l[c]-m); SS += ee[c]; }
    float p[CC_];
    #pragma unroll
    for (int c = 0; c < CC_; ++c) p[c] = ee[c]/SS;
    float best = p[0]; pc = 0;
    #pragma unroll
    for (int c = 1; c < CC_; ++c){ if (p[c] > best){ best = p[c]; pc = c; } }
    bw = 0;
    #pragma unroll
    for (int c = 0; c < CC_; ++c){
      int b = (int)(p[c]*15.0f); b = b > 14 ? 14 : b;
      bw |= (unsigned)b << (4*c);
    }
  }
  bw_out = bw; pc_out = pc;
}

__global__ __launch_bounds__(256, 4) void nectar_binning_kernel(
    const float* __restrict__ logits,
    const float* __restrict__ vf,
    float* __restrict__ out){
  __shared__ float s_vf[CC_*144];                  // [c][bin][nn]: c*144 + b*9 + nn
  __shared__ unsigned int s_oneh[(TH+2)*OHS];

  const int tid = threadIdx.x;

  // XCD-bijective swizzle: NWG%8==0, consecutive virt ids stay on one XCD
  const int lin  = blockIdx.x;
  const int virt = (lin & 7) * (NWG/8) + (lin >> 3);
  const int bz   = virt >> 8;            // 256 tiles per batch
  const int rem  = virt & 255;
  const int h0   = (rem >> 4) * TH;      // 16 tile-rows
  const int w0   = (rem & 15) * TW;      // 16 tile-cols
  const long base_b = (long)bz * (CC_*HH*WW);

  const int tx = tid & 7;                // w-quad (4 px)
  const int ty = tid >> 3;               // row 0..31

  // ---- issue ALL global loads up front: interior strip (8 x float4), then halo ----
  const int gw = w0 + 4*tx;
  const int gh = h0 + ty;
  const float* lp = logits + base_b + (long)gh*WW + gw;
  float4 lv[CC_];
  #pragma unroll
  for (int c = 0; c < CC_; ++c) lv[c] = *reinterpret_cast<const float4*>(lp + (long)c*(HH*WW));

  float hl[CC_]; bool hval = false; int hr = 0, hc = 0;
  if (tid < 132){
    int r, c;
    if      (tid < 34){ r = -1;       c = tid - 1;  }
    else if (tid < 68){ r = TH;       c = tid - 35; }
    else if (tid < 100){ r = tid-68;  c = -1;       }
    else               { r = tid-100; c = TW;       }
    hr = r; hc = c;
    const int hh = h0 + r, ww = w0 + c;
    hval = (hh >= 0 && hh < HH && ww >= 0 && ww < WW);
    const int hhc = min(max(hh,0),HH-1), wwc = min(max(ww,0),WW-1);
    const float* hp = logits + base_b + (long)hhc*WW + wwc;
    #pragma unroll
    for (int c2 = 0; c2 < CC_; ++c2) hl[c2] = hp[(long)c2*(HH*WW)];
  }

  // stage calibration table (LDS writes overlap load latency)
  for (int i = tid; i < CC_*9*15; i += 256){
    int b = i % 15, q = i / 15;
    int nn = q % 9, c = q / 9;
    s_vf[c*144 + b*9 + nn] = vf[i];
  }

  unsigned int binw[4];

  // ---- interior compute ----
  #pragma unroll
  for (int i = 0; i < 4; ++i){
    float l[CC_];
    #pragma unroll
    for (int c = 0; c < CC_; ++c) l[c] = comp4(lv[c], i);
    int pc; px_bins(l, binw[i], pc);
    s_oneh[(ty+1)*OHS + 4*tx + i + 1] = 1u << (4*pc);
  }

  // ---- halo argmax (loads in flight since kernel top) ----
  if (tid < 132){
    unsigned int oh = 0u;
    if (hval){
      float b1 = hl[0], b2 = -1e30f; int pc = 0;
      #pragma unroll
      for (int c2 = 1; c2 < CC_; ++c2){
        bool gt = hl[c2] > b1;
        b2 = gt ? b1 : fmaxf(b2, hl[c2]);
        pc = gt ? c2 : pc;
        b1 = gt ? hl[c2] : b1;
      }
      if (b1 - b2 < 1e-5f){
        float e[CC_]; float S = 0.f;
        #pragma unroll
        for (int c2 = 0; c2 < CC_; ++c2){ e[c2] = expf(hl[c2]-b1); S += e[c2]; }
        float p[CC_];
        #pragma unroll
        for (int c2 = 0; c2 < CC_; ++c2) p[c2] = e[c2]/S;
        float best = p[0]; pc = 0;
        #pragma unroll
        for (int c2 = 1; c2 < CC_; ++c2){ if (p[c2] > best){ best = p[c2]; pc = c2; } }
      }
      oh = 1u << (4*pc);
    }
    s_oneh[(hr+1)*OHS + hc + 1] = oh;
  }

  __syncthreads();

  // ---- epilogue: 3x3 nibble histogram, gather, normalize, NT store ----
  unsigned int cs[6];
  #pragma unroll
  for (int kk = 0; kk < 6; ++kk){
    int cidx = 4*tx + kk;
    cs[kk] = s_oneh[ ty   *OHS + cidx]
           + s_oneh[(ty+1)*OHS + cidx]
           + s_oneh[(ty+2)*OHS + cidx];
  }
  float4 o[CC_];
  #pragma unroll
  for (int i = 0; i < 4; ++i){
    unsigned int ctr = s_oneh[(ty+1)*OHS + 4*tx + i + 1];
    unsigned int acc = cs[i] + cs[i+1] + cs[i+2] - ctr;
    unsigned int valid = (acc * 0x11111111u) >> 28;
    unsigned int bw = binw[i];
    float v[CC_]; float S2 = 0.f;
    #pragma unroll
    for (int c = 0; c < CC_; ++c){
      unsigned int nc = (acc >> (4*c)) & 0xFu;
      unsigned int nn = ((ctr >> (4*c)) & 1u) ? nc : (valid - nc);
      unsigned int b  = (bw  >> (4*c)) & 0xFu;
      float t = s_vf[c*144 + b*9 + nn];
      v[c] = t; S2 += t;
    }
    float r2 = 1.0f / S2;
    #pragma unroll
    for (int c = 0; c < CC_; ++c){
      float res = v[c]*r2;
      if(i==0) o[c].x = res; else if(i==1) o[c].y = res; else if(i==2) o[c].z = res; else o[c].w = res;
    }
  }
  #pragma unroll
  for (int c = 0; c < CC_; ++c){
    vfloat4 nv = { o[c].x, o[c].y, o[c].z, o[c].w };
    __builtin_nontemporal_store(nv,
      reinterpret_cast<vfloat4*>(out + base_b + (long)c*(HH*WW) + (long)gh*WW + gw));
  }
}

extern "C" void kernel_launch(void* const* d_in, const int* in_sizes, int n_in,
                              void* d_out, int out_size, void* d_ws, size_t ws_size,
                              hipStream_t stream){
  const float* logits = (const float*)d_in[0];
  const float* vf     = (const float*)d_in[1];
  float* out          = (float*)d_out;
  nectar_binning_kernel<<<dim3(NWG), 256, 0, stream>>>(logits, vf, out);
}